// Round 10
// baseline (534.255 us; speedup 1.0000x reference)
//
#include <hip/hip_runtime.h>

// SkipLSTM: B=256, T=784, I=1, H=110, NCLS=10
// R10 = R8 geometry (verified pass, 529us) + safe fixes only.
// One block per batch element, 448 threads = 7 waves.
// Quad per unit u; lane j owns cols [28j,28j+28) of gate rows
// {u, u+110, u+220, u+330} as f16 pairs (56 half2); v_dot2_f32_f16 MACs.
// FIX vs R8: bias/x-term folded on quad-lane 0 ONLY (R3-R8 counted it
// lane-count times; absmax halved 0.315->0.159 going 8->4 lanes = the tell).
// R9's 2-lane restructure broke the c-dynamics (cnt 200704 -> 2880) and is
// fully reverted. p-reads hoisted before h-reads (du hides under ds_read
// latency); t-loop unrolled x4. One barrier/step; h(f16),p double-buffered;
// du pipelined (du_{t-1} under step t); single-instr asm DPP ops.

#define T784 784
#define H110 110
#define NT   448
#define NCLS 10
#define LOG2E 1.44269504088896340736f

typedef _Float16 h2 __attribute__((ext_vector_type(2)));
typedef _Float16 h4 __attribute__((ext_vector_type(4)));

__device__ __forceinline__ float frcp(float x)  { return __builtin_amdgcn_rcpf(x); }
__device__ __forceinline__ float fexp2(float x) { return __builtin_amdgcn_exp2f(x); }

// single-instruction DPP adds (src0 carries the DPP swizzle)
__device__ __forceinline__ float add_q1(float v) {  // xor1 within quad
    float d; asm("v_add_f32_dpp %0, %1, %1 quad_perm:[1,0,3,2] row_mask:0xf bank_mask:0xf bound_ctrl:0"
                 : "=v"(d) : "v"(v)); return d;
}
__device__ __forceinline__ float add_q2(float v) {  // xor2 within quad
    float d; asm("v_add_f32_dpp %0, %1, %1 quad_perm:[2,3,0,1] row_mask:0xf bank_mask:0xf bound_ctrl:0"
                 : "=v"(d) : "v"(v)); return d;
}
__device__ __forceinline__ float add_hm(float v) {  // xor4 (row_half_mirror)
    float d; asm("v_add_f32_dpp %0, %1, %1 row_half_mirror row_mask:0xf bank_mask:0xf bound_ctrl:0"
                 : "=v"(d) : "v"(v)); return d;
}
__device__ __forceinline__ float add_rm(float v) {  // xor8 (row_mirror)
    float d; asm("v_add_f32_dpp %0, %1, %1 row_mirror row_mask:0xf bank_mask:0xf bound_ctrl:0"
                 : "=v"(d) : "v"(v)); return d;
}
__device__ __forceinline__ float add_b15(float v) { // row_bcast:15
    float d; asm("v_add_f32_dpp %0, %1, %1 row_bcast:15 row_mask:0xf bank_mask:0xf bound_ctrl:0"
                 : "=v"(d) : "v"(v)); return d;
}
__device__ __forceinline__ float add_b31(float v) { // row_bcast:31
    float d; asm("v_add_f32_dpp %0, %1, %1 row_bcast:31 row_mask:0xf bank_mask:0xf bound_ctrl:0"
                 : "=v"(d) : "v"(v)); return d;
}
template <int L>
__device__ __forceinline__ float qbcast(float v) {  // broadcast quad-lane L
    float d;
    if (L == 0) asm("v_mov_b32_dpp %0, %1 quad_perm:[0,0,0,0] row_mask:0xf bank_mask:0xf bound_ctrl:0" : "=v"(d) : "v"(v));
    if (L == 1) asm("v_mov_b32_dpp %0, %1 quad_perm:[1,1,1,1] row_mask:0xf bank_mask:0xf bound_ctrl:0" : "=v"(d) : "v"(v));
    if (L == 2) asm("v_mov_b32_dpp %0, %1 quad_perm:[2,2,2,2] row_mask:0xf bank_mask:0xf bound_ctrl:0" : "=v"(d) : "v"(v));
    if (L == 3) asm("v_mov_b32_dpp %0, %1 quad_perm:[3,3,3,3] row_mask:0xf bank_mask:0xf bound_ctrl:0" : "=v"(d) : "v"(v));
    return d;
}

__global__ __launch_bounds__(NT, 2)
void skiplstm_kernel(const float* __restrict__ x,
                     const float* __restrict__ W_ih,
                     const float* __restrict__ W_hh,
                     const float* __restrict__ b,
                     const float* __restrict__ W_p,
                     const float* __restrict__ b_p,
                     const float* __restrict__ h0,
                     const float* __restrict__ c0,
                     const float* __restrict__ W_fc,
                     const float* __restrict__ b_fc,
                     float* __restrict__ out)
{
    __shared__ __align__(16) _Float16 s_h16[256]; // double-buffered h f16 (128 each)
    __shared__ float s_pbuf[256];                 // double-buffered c*W_p' partials
    __shared__ float s_x[T784];

    const int tid  = threadIdx.x;
    const int bb   = blockIdx.x;
    const int unit = tid >> 2;                   // 0..111 (110,111 inactive)
    const int j    = tid & 3;                    // k-slice lane
    const bool act = (unit < H110);

    // ---- f16 weight pairs, pre-scaled by -LOG2E (g-row: -2LOG2E) ----
    h2 w2[4][14];
    float bv[4], wv[4];
    #pragma unroll
    for (int g = 0; g < 4; ++g) {
        const float ws = (g == 2) ? (-2.0f * LOG2E) : (-LOG2E);
        const int row = unit + H110 * g;
        // BIAS FIX: fold b/W_ih on quad-lane 0 only (counted once post-reduce)
        bv[g] = (act && j == 0) ? b[row]    * ws : 0.0f;
        wv[g] = (act && j == 0) ? W_ih[row] * ws : 0.0f;
        const float* rp = W_hh + row * H110;
        #pragma unroll
        for (int m = 0; m < 14; ++m) {
            const int k = 28 * j + 2 * m;
            float f0 = 0.f, f1 = 0.f;
            if (act) {
                if (k + 0 < H110) f0 = rp[k + 0] * ws;
                if (k + 1 < H110) f1 = rp[k + 1] * ws;
            }
            w2[g][m].x = (_Float16)f0;
            w2[g][m].y = (_Float16)f1;
        }
    }
    float creg = act ? c0[unit] : 0.0f;          // f32 state, replicated in quad
    float hreg = act ? h0[unit] : 0.0f;
    const float wpn = act ? (-LOG2E) * W_p[unit] : 0.0f;  // pre-scaled
    const float bpn = (-LOG2E) * b_p[0];

    // lane j activates gate j; gate 2 (g) is tanh = 2*sigm(2x)-1
    const float mulc = (j == 2) ? 2.0f : 1.0f;
    const float addc = (j == 2) ? -1.0f : 0.0f;

    for (int i = tid; i < 256;  i += NT) { s_h16[i] = (_Float16)0.f; s_pbuf[i] = 0.0f; }
    for (int i = tid; i < T784; i += NT) s_x[i] = x[bb * T784 + i];
    __syncthreads();
    if (tid < H110) s_h16[tid] = (_Float16)h0[tid];  // buf0 init
    __syncthreads();

    float u_prev = 1.0f;                         // replicated per-wave (identical)
    int   cnt    = 0;

    auto step = [&](const _Float16* hb, _Float16* hn,
                    const float* pp, float* pn, int t, bool first) {
        // ---- p-reads FIRST (du math hides under the h-read latency) ----
        const int lane = tid & 63;
        const float p0 = pp[lane], p1 = pp[lane + 64];
        const float xt = s_x[t];
        const h4* hp = (const h4*)hb + 7 * j;    // f16 [28j, 28j+28), 8B-aligned
        const h4 hh0 = hp[0], hh1 = hp[1], hh2 = hp[2], hh3 = hp[3];
        const h4 hh4 = hp[4], hh5 = hp[5], hh6 = hp[6];

        h2 hv[14];
        hv[0]  = __builtin_shufflevector(hh0, hh0, 0, 1);
        hv[1]  = __builtin_shufflevector(hh0, hh0, 2, 3);
        hv[2]  = __builtin_shufflevector(hh1, hh1, 0, 1);
        hv[3]  = __builtin_shufflevector(hh1, hh1, 2, 3);
        hv[4]  = __builtin_shufflevector(hh2, hh2, 0, 1);
        hv[5]  = __builtin_shufflevector(hh2, hh2, 2, 3);
        hv[6]  = __builtin_shufflevector(hh3, hh3, 0, 1);
        hv[7]  = __builtin_shufflevector(hh3, hh3, 2, 3);
        hv[8]  = __builtin_shufflevector(hh4, hh4, 0, 1);
        hv[9]  = __builtin_shufflevector(hh4, hh4, 2, 3);
        hv[10] = __builtin_shufflevector(hh5, hh5, 0, 1);
        hv[11] = __builtin_shufflevector(hh5, hh5, 2, 3);
        hv[12] = __builtin_shufflevector(hh6, hh6, 0, 1);
        hv[13] = __builtin_shufflevector(hh6, hh6, 2, 3);

        // ---- 56 v_dot2_f32_f16; bias/x folded once (lane0-only constants) ----
        float a0 = fmaf(xt, wv[0], bv[0]);
        float a1 = fmaf(xt, wv[1], bv[1]);
        float a2 = fmaf(xt, wv[2], bv[2]);
        float a3 = fmaf(xt, wv[3], bv[3]);
        #pragma unroll
        for (int m = 0; m < 14; ++m) {
            a0 = __builtin_amdgcn_fdot2(hv[m], w2[0][m], a0, false);
            a1 = __builtin_amdgcn_fdot2(hv[m], w2[1][m], a1, false);
            a2 = __builtin_amdgcn_fdot2(hv[m], w2[2][m], a2, false);
            a3 = __builtin_amdgcn_fdot2(hv[m], w2[3][m], a3, false);
        }

        // ---- pipelined du_{t-1} -> u_t (hidden under the dot2 block) ----
        float u_now;
        if (first) {
            u_now = 1.0f;                        // u0 = 1
        } else {
            float v = p0 + p1;
            v = add_q1(v); v = add_q2(v); v = add_hm(v);
            v = add_rm(v); v = add_b15(v); v = add_b31(v);
            const float tot = __int_as_float(
                __builtin_amdgcn_readlane(__float_as_int(v), 63));
            const float du = frcp(1.0f + fexp2(tot + bpn));      // sigm
            u_now = (u_prev > 0.5f) ? du
                                    : (u_prev + fminf(du, 1.0f - u_prev));
        }
        const bool up = u_now > 0.5f;            // == round-half-even on [0,1]
        cnt += up ? 1 : 0;
        u_prev = u_now;

        // ---- quad allreduce (2 single-instr DPP levels) ----
        a0 = add_q1(a0); a1 = add_q1(a1); a2 = add_q1(a2); a3 = add_q1(a3);
        a0 = add_q2(a0); a1 = add_q2(a1); a2 = add_q2(a2); a3 = add_q2(a3);

        // ---- lane j activates gate j (pre-scaled: no mul) ----
        const float t01  = (j & 1) ? a1 : a0;
        const float t23  = (j & 1) ? a3 : a2;
        const float asel = (j & 2) ? t23 : t01;
        const float av   = fmaf(mulc, frcp(1.0f + fexp2(asel)), addc);
        const float gi = qbcast<0>(av);
        const float gf = qbcast<1>(av);
        const float gg = qbcast<2>(av);
        const float go = qbcast<3>(av);

        const float c_new = fmaf(gf, creg, gi * gg);
        const float th    = fmaf(2.0f, frcp(1.0f + fexp2(c_new * (-2.0f * LOG2E))), -1.0f);
        const float h_new = go * th;
        creg = up ? c_new : creg;                // ub is exactly 0/1
        hreg = up ? h_new : hreg;
        if (act && j == 0) {
            hn[unit] = (_Float16)hreg;           // b16 write
            pn[unit] = creg * wpn;               // next step's du input (f32)
        }
        __syncthreads();                         // the ONLY barrier per step
    };

    _Float16* const h0b = s_h16;
    _Float16* const h1b = s_h16 + 128;
    float* const p0b = s_pbuf;
    float* const p1b = s_pbuf + 128;

    step(h0b, h1b, p0b, p1b, 0, true);           // peeled: no du before step 0
    step(h1b, h0b, p1b, p0b, 1, false);
    step(h0b, h1b, p0b, p1b, 2, false);
    step(h1b, h0b, p1b, p0b, 3, false);
    for (int t = 4; t < T784; t += 4) {          // x4 unroll: less loop control
        step(h0b, h1b, p0b, p1b, t,     false);
        step(h1b, h0b, p1b, p0b, t + 1, false);
        step(h0b, h1b, p0b, p1b, t + 2, false);
        step(h1b, h0b, p1b, p0b, t + 3, false);
    }

    // epilogue: final h is in buffer 0 (t=783 writes buf 0)
    if (tid < NCLS) {
        float acc = b_fc[tid];
        for (int k = 0; k < H110; ++k)
            acc = fmaf((float)s_h16[k], W_fc[tid * H110 + k], acc);
        out[bb * NCLS + tid] = acc;
    }
    if (tid == 0)
        atomicAdd(out + 256 * NCLS, (float)cnt); // total_u at flat index 2560
}

__global__ void zero_tail_kernel(float* out) {
    if (threadIdx.x == 0) out[256 * NCLS] = 0.0f;   // d_out is poisoned 0xAA
}

extern "C" void kernel_launch(void* const* d_in, const int* in_sizes, int n_in,
                              void* d_out, int out_size, void* d_ws, size_t ws_size,
                              hipStream_t stream) {
    const float* x    = (const float*)d_in[0];
    const float* W_ih = (const float*)d_in[1];
    const float* W_hh = (const float*)d_in[2];
    const float* b    = (const float*)d_in[3];
    const float* W_p  = (const float*)d_in[4];
    const float* b_p  = (const float*)d_in[5];
    const float* h0   = (const float*)d_in[6];
    const float* c0   = (const float*)d_in[7];
    const float* W_fc = (const float*)d_in[8];
    const float* b_fc = (const float*)d_in[9];
    float* out = (float*)d_out;

    zero_tail_kernel<<<1, 64, 0, stream>>>(out);
    skiplstm_kernel<<<256, NT, 0, stream>>>(x, W_ih, W_hh, b, W_p, b_p,
                                            h0, c0, W_fc, b_fc, out);
}